// Round 16
// baseline (151.464 us; speedup 1.0000x reference)
//
#include <hip/hip_runtime.h>

typedef float f2 __attribute__((ext_vector_type(2)));

#define HW 64
#define XR (66*64)       // staging region: 66 rows x 64 cols (rows 0,65 = zero pad)
#define LH 150
#define LQ 10

// Full-wave lane shifts; bound_ctrl zero-fill == SAME padding at cols 0/63.
__device__ __forceinline__ float dpp_wshr1(float x) {   // lane i <- lane i-1
    return __builtin_bit_cast(float, __builtin_amdgcn_update_dpp(
        0, __builtin_bit_cast(int, x), 0x138, 0xF, 0xF, true));
}
__device__ __forceinline__ float dpp_wshl1(float x) {   // lane i <- lane i+1
    return __builtin_bit_cast(float, __builtin_amdgcn_update_dpp(
        0, __builtin_bit_cast(int, x), 0x130, 0xF, 0xF, true));
}
__device__ __forceinline__ f2 dpp2_shr(f2 v) { return (f2){dpp_wshr1(v.x), dpp_wshr1(v.y)}; }
__device__ __forceinline__ f2 dpp2_shl(f2 v) { return (f2){dpp_wshl1(v.x), dpp_wshl1(v.y)}; }

// VOP3P packed fp32 FMA, weight broadcast from one word of an SGPR pair
// (weights wave-uniform; VOP3P allows one SGPR source — R14).
__device__ __forceinline__ f2 pk_fma_b0(f2 a, f2 wpair, f2 c) {
    f2 d;
    asm("v_pk_fma_f32 %0, %1, %2, %3 op_sel_hi:[1,0,1]"
        : "=v"(d) : "v"(a), "s"(wpair), "v"(c));
    return d;
}
__device__ __forceinline__ f2 pk_fma_b1(f2 a, f2 wpair, f2 c) {
    f2 d;
    asm("v_pk_fma_f32 %0, %1, %2, %3 op_sel:[0,1,0]"
        : "=v"(d) : "v"(a), "s"(wpair), "v"(c));
    return d;
}

// One block per image, 1024 threads = 16 waves = 4 waves/SIMD. lane l = column;
// wave w owns rows 4w..4w+3 in registers (2 f2 row-pairs). Horizontal halos via
// wave DPP; vertical halos via LDS parity slots. The iteration is SPLIT around
// the barrier (R16): interior taps (120 pk, no ht/hb dependence) issue before
// __syncthreads, so barrier skew + the post-barrier ds_read latency overlap
// real FMA work instead of idling all 16 waves in lockstep (R15: ~24us stall).
__global__ __launch_bounds__(1024)
void vin_main(const float* __restrict__ X,
              const float* __restrict__ h_w,
              const float* __restrict__ h_b,
              const float* __restrict__ r_w,
              const float* __restrict__ q_w,
              const float* __restrict__ wgt,
              const int* __restrict__ kptr,
              float* __restrict__ out) {
    __shared__ float smem[3*XR + 32];      // X0 | X1 | r | weff stash (32)
    float* sR  = smem + 2*XR;
    float* sWE = smem + 3*XR;
    // halo slots alias dead X region after prologue: [2][17][64] each
    float* sHB = smem;                     // bottom rows; wave w writes [p][w+1]; pad [p][0]=0
    float* sHT = smem + 2176;              // top rows; wave w writes [p][w]; pad [p][16]=0

    const int b = blockIdx.x, tid = threadIdx.x;
    const int w = tid >> 6, l = tid & 63;

    for (int i = tid; i < 3*XR + 32; i += 1024) smem[i] = 0.f;
    __syncthreads();

    // ---- fused weff: wave w computes outputs j = w, w+16 (j<19) ----
    #pragma unroll
    for (int i = 0; i < 2; ++i) {
        int j = w + 16*i;
        if (j < 19) {
            float s = 0.f;
            #pragma unroll
            for (int u = 0; u < 3; ++u) {
                int t = l + 64*u;
                if (t < LH) {
                    float src = (j < 18) ? h_w[t*18 + j] : h_b[t];
                    s = fmaf(r_w[t], src, s);
                }
            }
            #pragma unroll
            for (int off = 32; off >= 1; off >>= 1)
                s += __shfl_xor(s, off);
            if (l == 0) sWE[j] = s;
        }
    }

    // ---- stage X (both channels), image rows 0..63 -> LDS rows 1..64 ----
    const float* Xb = X + (size_t)b * 2 * HW * HW;
    for (int i = tid; i < 2*64*16; i += 1024) {
        int ch = i >> 10, j = i & 1023, row = j >> 4, c = j & 15;
        float4 v = *(const float4*)(Xb + ((size_t)ch*HW + row)*HW + c*4);
        *(float4*)(smem + ch*XR + (row+1)*64 + c*4) = v;
    }
    __syncthreads();

    // ---- r = conv3x3(X, weff) + beff, column mapping (4 owned rows) ----
    float wE[19];
    #pragma unroll
    for (int i = 0; i < 19; ++i) wE[i] = sWE[i];
    float rloc[4];
    {
        float xc[2][6], xl[2][6], xr[2][6];
        #pragma unroll
        for (int ch = 0; ch < 2; ++ch)
            #pragma unroll
            for (int k = 0; k < 6; ++k) {
                xc[ch][k] = smem[ch*XR + (4*w + k)*64 + l];   // global row 4w-1+k
                xl[ch][k] = dpp_wshr1(xc[ch][k]);
                xr[ch][k] = dpp_wshl1(xc[ch][k]);
            }
        #pragma unroll
        for (int i = 0; i < 4; ++i) {
            float acc = wE[18];
            #pragma unroll
            for (int ch = 0; ch < 2; ++ch)
                #pragma unroll
                for (int dy = 0; dy < 3; ++dy) {
                    acc = fmaf(xl[ch][i+dy], wE[ch*9 + dy*3 + 0], acc);
                    acc = fmaf(xc[ch][i+dy], wE[ch*9 + dy*3 + 1], acc);
                    acc = fmaf(xr[ch][i+dy], wE[ch*9 + dy*3 + 2], acc);
                }
            rloc[i] = acc;
        }
    }
    #pragma unroll
    for (int i = 0; i < 4; ++i) sR[(4*w + i + 1)*64 + l] = rloc[i];
    __syncthreads();   // X regions dead after this -> halo slots may alias

    // ---- qr[a] = conv3x3(r, q_w[a]); v0 = max_a qr ----
    f2 qr[LQ][2];
    f2 vc[2];
    {
        float rc[6], rl[6], rr2[6];
        #pragma unroll
        for (int k = 0; k < 6; ++k) {
            rc[k]  = sR[(4*w + k)*64 + l];
            rl[k]  = dpp_wshr1(rc[k]);
            rr2[k] = dpp_wshl1(rc[k]);
        }
        float vcur[4];
        #pragma unroll
        for (int a = 0; a < LQ; ++a) {
            float qa[9];
            #pragma unroll
            for (int i = 0; i < 9; ++i) qa[i] = q_w[a*9 + i];
            float acc[4];
            #pragma unroll
            for (int i = 0; i < 4; ++i) {
                float s = 0.f;
                #pragma unroll
                for (int dy = 0; dy < 3; ++dy) {
                    s = fmaf(rl[i+dy],  qa[dy*3 + 0], s);
                    s = fmaf(rc[i+dy],  qa[dy*3 + 1], s);
                    s = fmaf(rr2[i+dy], qa[dy*3 + 2], s);
                }
                acc[i] = s;
                vcur[i] = a ? fmaxf(vcur[i], s) : s;
            }
            qr[a][0] = (f2){acc[0], acc[1]};
            qr[a][1] = (f2){acc[2], acc[3]};
        }
        vc[0] = (f2){vcur[0], vcur[1]};
        vc[1] = (f2){vcur[2], vcur[3]};
    }
    // zero the 4 halo pad rows (alias region; X dead since last barrier)
    if (tid < 256) {
        int p = tid >> 7, half = (tid >> 6) & 1, ll = tid & 63;
        if (half == 0) sHB[p*1088 + 0*64  + ll] = 0.f;
        else           sHT[p*1088 + 16*64 + ll] = 0.f;
    }

    // ---- weights as 45 packed pairs (wave-uniform -> SGPRs) ----
    f2 wv2[LQ][5];
    #pragma unroll
    for (int a = 0; a < LQ; ++a) {
        #pragma unroll
        for (int p = 0; p < 4; ++p)
            wv2[a][p] = (f2){wgt[a*9 + 2*p], wgt[a*9 + 2*p + 1]};
        wv2[a][4] = (f2){wgt[a*9 + 8], 0.f};
    }

    // ---- value iteration: v <- max_a (qr[a] + conv3x3(v, w[a])) ----
    // taps for pair j: dy=0 -> P[j] (w0,w1,w2), dy=1 -> vc[j] (w3,w4,w5),
    // dy=2 -> P[j+1] (w6,w7,w8). P[0] needs ht, P[2] needs hb -> post-barrier.
    const int km1 = kptr[0] - 1;
    const int wrB = (w+1)*64 + l;   // my bottom-row slot / partner's top-halo index
    const int wrT = w*64 + l;
    for (int t = 0; t < km1; ++t) {
        const int p = (t & 1) * 1088;
        sHB[p + wrB] = vc[1].y;     // my row 4w+3
        sHT[p + wrT] = vc[0].x;     // my row 4w

        // ===== pre-barrier: interior taps (no ht/hb dependence) =====
        f2 P1  = (f2){vc[0].y, vc[1].x};
        f2 PL1 = dpp2_shr(P1),    PR1 = dpp2_shl(P1);
        f2 OL0 = dpp2_shr(vc[0]), OR0 = dpp2_shl(vc[0]);
        f2 OL1 = dpp2_shr(vc[1]), OR1 = dpp2_shl(vc[1]);
        f2 vn[LQ][2];
        #pragma unroll
        for (int a = 0; a < LQ; ++a) {
            f2 a0 = qr[a][0];
            a0 = pk_fma_b1(OL0,   wv2[a][1], a0);  // w3
            a0 = pk_fma_b0(vc[0], wv2[a][2], a0);  // w4
            a0 = pk_fma_b1(OR0,   wv2[a][2], a0);  // w5
            a0 = pk_fma_b0(PL1,   wv2[a][3], a0);  // w6
            a0 = pk_fma_b1(P1,    wv2[a][3], a0);  // w7
            a0 = pk_fma_b0(PR1,   wv2[a][4], a0);  // w8
            f2 a1 = qr[a][1];
            a1 = pk_fma_b0(PL1,   wv2[a][0], a1);  // w0
            a1 = pk_fma_b1(P1,    wv2[a][0], a1);  // w1
            a1 = pk_fma_b0(PR1,   wv2[a][1], a1);  // w2
            a1 = pk_fma_b1(OL1,   wv2[a][1], a1);  // w3
            a1 = pk_fma_b0(vc[1], wv2[a][2], a1);  // w4
            a1 = pk_fma_b1(OR1,   wv2[a][2], a1);  // w5
            vn[a][0] = a0; vn[a][1] = a1;
        }

        __syncthreads();

        // ===== post-barrier: halo taps + max =====
        float ht = sHB[p + wrT];    // row 4w-1 (zero for w==0)
        float hb = sHT[p + wrB];    // row 4w+4 (zero for w==15)
        f2 P0  = (f2){ht,       vc[0].x};
        f2 P2  = (f2){vc[1].y,  hb};
        f2 PL0 = dpp2_shr(P0), PR0 = dpp2_shl(P0);
        f2 PL2 = dpp2_shr(P2), PR2 = dpp2_shl(P2);
        f2 m0, m1;
        #pragma unroll
        for (int a = 0; a < LQ; ++a) {
            f2 a0 = vn[a][0];
            a0 = pk_fma_b0(PL0, wv2[a][0], a0);    // w0
            a0 = pk_fma_b1(P0,  wv2[a][0], a0);    // w1
            a0 = pk_fma_b0(PR0, wv2[a][1], a0);    // w2
            f2 a1 = vn[a][1];
            a1 = pk_fma_b0(PL2, wv2[a][3], a1);    // w6
            a1 = pk_fma_b1(P2,  wv2[a][3], a1);    // w7
            a1 = pk_fma_b0(PR2, wv2[a][4], a1);    // w8
            m0 = (a == 0) ? a0 : __builtin_elementwise_max(m0, a0);
            m1 = (a == 0) ? a1 : __builtin_elementwise_max(m1, a1);
        }
        vc[0] = m0; vc[1] = m1;
    }

    // ---- write out: lane l -> column l, rows 4w..4w+3 (coalesced per wave) ----
    float* ob = out + (size_t)b*HW*HW + (size_t)(4*w)*HW + l;
    ob[0*HW] = vc[0].x;
    ob[1*HW] = vc[0].y;
    ob[2*HW] = vc[1].x;
    ob[3*HW] = vc[1].y;
}

extern "C" void kernel_launch(void* const* d_in, const int* in_sizes, int n_in,
                              void* d_out, int out_size, void* d_ws, size_t ws_size,
                              hipStream_t stream) {
    const float* X   = (const float*)d_in[0];
    const float* h_w = (const float*)d_in[1];
    const float* h_b = (const float*)d_in[2];
    const float* r_w = (const float*)d_in[3];
    const float* q_w = (const float*)d_in[4];
    const float* w   = (const float*)d_in[5];
    const int*   k   = (const int*)d_in[6];
    float* out = (float*)d_out;

    vin_main<<<128, 1024, 0, stream>>>(X, h_w, h_b, r_w, q_w, w, k, out);
}

// Round 17
// 145.671 us; speedup vs baseline: 1.0398x; 1.0398x over previous
//
#include <hip/hip_runtime.h>

typedef float f2 __attribute__((ext_vector_type(2)));

#define HW 64
#define XR (66*64)       // staging region: 66 rows x 64 cols (rows 0,65 = zero pad)
#define LH 150
#define LQ 10

// Full-wave lane shifts; bound_ctrl zero-fill == SAME padding at cols 0/63.
__device__ __forceinline__ float dpp_wshr1(float x) {   // lane i <- lane i-1
    return __builtin_bit_cast(float, __builtin_amdgcn_update_dpp(
        0, __builtin_bit_cast(int, x), 0x138, 0xF, 0xF, true));
}
__device__ __forceinline__ float dpp_wshl1(float x) {   // lane i <- lane i+1
    return __builtin_bit_cast(float, __builtin_amdgcn_update_dpp(
        0, __builtin_bit_cast(int, x), 0x130, 0xF, 0xF, true));
}
__device__ __forceinline__ f2 dpp2_shr(f2 v) { return (f2){dpp_wshr1(v.x), dpp_wshr1(v.y)}; }
__device__ __forceinline__ f2 dpp2_shl(f2 v) { return (f2){dpp_wshl1(v.x), dpp_wshl1(v.y)}; }

// VOP3P packed fp32 FMA, weight broadcast from one word of an SGPR pair
// (weights wave-uniform; VOP3P allows one SGPR source — R14).
__device__ __forceinline__ f2 pk_fma_b0(f2 a, f2 wpair, f2 c) {
    f2 d;
    asm("v_pk_fma_f32 %0, %1, %2, %3 op_sel_hi:[1,0,1]"
        : "=v"(d) : "v"(a), "s"(wpair), "v"(c));
    return d;
}
__device__ __forceinline__ f2 pk_fma_b1(f2 a, f2 wpair, f2 c) {
    f2 d;
    asm("v_pk_fma_f32 %0, %1, %2, %3 op_sel:[0,1,0]"
        : "=v"(d) : "v"(a), "s"(wpair), "v"(c));
    return d;
}

// One block per image, 1024 threads = 16 waves = 4 waves/SIMD. lane l = column;
// wave w owns rows 4w..4w+3 in registers (2 f2 row-pairs). Horizontal halos via
// wave DPP; vertical halos via 2 ds_write_b32 + 2 ds_read_b32 per lane per iter
// (parity slots, 1 barrier/iter). Weights in SGPRs (R14); 4 waves/SIMD (R15).
// R13/R16 barrier-splits both regressed — this is the proven best schedule.
__global__ __launch_bounds__(1024)
void vin_main(const float* __restrict__ X,
              const float* __restrict__ h_w,
              const float* __restrict__ h_b,
              const float* __restrict__ r_w,
              const float* __restrict__ q_w,
              const float* __restrict__ wgt,
              const int* __restrict__ kptr,
              float* __restrict__ out) {
    __shared__ float smem[3*XR + 32];      // X0 | X1 | r | weff stash (32)
    float* sR  = smem + 2*XR;
    float* sWE = smem + 3*XR;
    // halo slots alias dead X region after prologue: [2][17][64] each
    float* sHB = smem;                     // bottom rows; wave w writes [p][w+1]; pad [p][0]=0
    float* sHT = smem + 2176;              // top rows; wave w writes [p][w]; pad [p][16]=0

    const int b = blockIdx.x, tid = threadIdx.x;
    const int w = tid >> 6, l = tid & 63;

    for (int i = tid; i < 3*XR + 32; i += 1024) smem[i] = 0.f;
    __syncthreads();

    // ---- fused weff: wave w computes outputs j = w, w+16 (j<19) ----
    #pragma unroll
    for (int i = 0; i < 2; ++i) {
        int j = w + 16*i;
        if (j < 19) {
            float s = 0.f;
            #pragma unroll
            for (int u = 0; u < 3; ++u) {
                int t = l + 64*u;
                if (t < LH) {
                    float src = (j < 18) ? h_w[t*18 + j] : h_b[t];
                    s = fmaf(r_w[t], src, s);
                }
            }
            #pragma unroll
            for (int off = 32; off >= 1; off >>= 1)
                s += __shfl_xor(s, off);
            if (l == 0) sWE[j] = s;
        }
    }

    // ---- stage X (both channels), image rows 0..63 -> LDS rows 1..64 ----
    const float* Xb = X + (size_t)b * 2 * HW * HW;
    for (int i = tid; i < 2*64*16; i += 1024) {
        int ch = i >> 10, j = i & 1023, row = j >> 4, c = j & 15;
        float4 v = *(const float4*)(Xb + ((size_t)ch*HW + row)*HW + c*4);
        *(float4*)(smem + ch*XR + (row+1)*64 + c*4) = v;
    }
    __syncthreads();

    // ---- r = conv3x3(X, weff) + beff, column mapping (4 owned rows) ----
    float wE[19];
    #pragma unroll
    for (int i = 0; i < 19; ++i) wE[i] = sWE[i];
    float rloc[4];
    {
        float xc[2][6], xl[2][6], xr[2][6];
        #pragma unroll
        for (int ch = 0; ch < 2; ++ch)
            #pragma unroll
            for (int k = 0; k < 6; ++k) {
                xc[ch][k] = smem[ch*XR + (4*w + k)*64 + l];   // global row 4w-1+k
                xl[ch][k] = dpp_wshr1(xc[ch][k]);
                xr[ch][k] = dpp_wshl1(xc[ch][k]);
            }
        #pragma unroll
        for (int i = 0; i < 4; ++i) {
            float acc = wE[18];
            #pragma unroll
            for (int ch = 0; ch < 2; ++ch)
                #pragma unroll
                for (int dy = 0; dy < 3; ++dy) {
                    acc = fmaf(xl[ch][i+dy], wE[ch*9 + dy*3 + 0], acc);
                    acc = fmaf(xc[ch][i+dy], wE[ch*9 + dy*3 + 1], acc);
                    acc = fmaf(xr[ch][i+dy], wE[ch*9 + dy*3 + 2], acc);
                }
            rloc[i] = acc;
        }
    }
    #pragma unroll
    for (int i = 0; i < 4; ++i) sR[(4*w + i + 1)*64 + l] = rloc[i];
    __syncthreads();   // X regions dead after this -> halo slots may alias

    // ---- qr[a] = conv3x3(r, q_w[a]); v0 = max_a qr ----
    f2 qr[LQ][2];
    f2 vc[2];
    {
        float rc[6], rl[6], rr2[6];
        #pragma unroll
        for (int k = 0; k < 6; ++k) {
            rc[k]  = sR[(4*w + k)*64 + l];
            rl[k]  = dpp_wshr1(rc[k]);
            rr2[k] = dpp_wshl1(rc[k]);
        }
        float vcur[4];
        #pragma unroll
        for (int a = 0; a < LQ; ++a) {
            float qa[9];
            #pragma unroll
            for (int i = 0; i < 9; ++i) qa[i] = q_w[a*9 + i];
            float acc[4];
            #pragma unroll
            for (int i = 0; i < 4; ++i) {
                float s = 0.f;
                #pragma unroll
                for (int dy = 0; dy < 3; ++dy) {
                    s = fmaf(rl[i+dy],  qa[dy*3 + 0], s);
                    s = fmaf(rc[i+dy],  qa[dy*3 + 1], s);
                    s = fmaf(rr2[i+dy], qa[dy*3 + 2], s);
                }
                acc[i] = s;
                vcur[i] = a ? fmaxf(vcur[i], s) : s;
            }
            qr[a][0] = (f2){acc[0], acc[1]};
            qr[a][1] = (f2){acc[2], acc[3]};
        }
        vc[0] = (f2){vcur[0], vcur[1]};
        vc[1] = (f2){vcur[2], vcur[3]};
    }
    // zero the 4 halo pad rows (alias region; X dead since last barrier)
    if (tid < 256) {
        int p = tid >> 7, half = (tid >> 6) & 1, ll = tid & 63;
        if (half == 0) sHB[p*1088 + 0*64  + ll] = 0.f;
        else           sHT[p*1088 + 16*64 + ll] = 0.f;
    }

    // ---- weights as 45 packed pairs (wave-uniform -> SGPRs) ----
    f2 wv2[LQ][5];
    #pragma unroll
    for (int a = 0; a < LQ; ++a) {
        #pragma unroll
        for (int p = 0; p < 4; ++p)
            wv2[a][p] = (f2){wgt[a*9 + 2*p], wgt[a*9 + 2*p + 1]};
        wv2[a][4] = (f2){wgt[a*9 + 8], 0.f};
    }

    // ---- value iteration: v <- max_a (qr[a] + conv3x3(v, w[a])) ----
    const int km1 = kptr[0] - 1;
    const int wrB = (w+1)*64 + l;   // my bottom-row slot / partner's top-halo index
    const int wrT = w*64 + l;
    for (int t = 0; t < km1; ++t) {
        const int p = (t & 1) * 1088;
        sHB[p + wrB] = vc[1].y;     // my row 4w+3
        sHT[p + wrT] = vc[0].x;     // my row 4w
        __syncthreads();
        float ht = sHB[p + wrT];    // row 4w-1 (zero for w==0)
        float hb = sHT[p + wrB];    // row 4w+4 (zero for w==15)

        // vv[0..5] = [ht, v0..v3, hb]; aligned pairs P[j]; odd pairs = vc[j]
        f2 P[3];
        P[0] = (f2){ht,       vc[0].x};
        P[1] = (f2){vc[0].y,  vc[1].x};
        P[2] = (f2){vc[1].y,  hb};
        f2 PL[3], PR[3], OL[2], OR[2];
        #pragma unroll
        for (int j = 0; j < 3; ++j) { PL[j] = dpp2_shr(P[j]); PR[j] = dpp2_shl(P[j]); }
        #pragma unroll
        for (int j = 0; j < 2; ++j) { OL[j] = dpp2_shr(vc[j]); OR[j] = dpp2_shl(vc[j]); }

        f2 vn[2];
        #pragma unroll
        for (int a = 0; a < LQ; ++a) {
            #pragma unroll
            for (int j = 0; j < 2; ++j) {
                // taps: dy=0 -> P[j], dy=1 -> vc[j] (odd), dy=2 -> P[j+1]; cols L/C/R
                f2 acc = qr[a][j];
                acc = pk_fma_b0(PL[j],   wv2[a][0], acc);  // w0
                acc = pk_fma_b1(P[j],    wv2[a][0], acc);  // w1
                acc = pk_fma_b0(PR[j],   wv2[a][1], acc);  // w2
                acc = pk_fma_b1(OL[j],   wv2[a][1], acc);  // w3
                acc = pk_fma_b0(vc[j],   wv2[a][2], acc);  // w4
                acc = pk_fma_b1(OR[j],   wv2[a][2], acc);  // w5
                acc = pk_fma_b0(PL[j+1], wv2[a][3], acc);  // w6
                acc = pk_fma_b1(P[j+1],  wv2[a][3], acc);  // w7
                acc = pk_fma_b0(PR[j+1], wv2[a][4], acc);  // w8
                vn[j] = (a == 0) ? acc : __builtin_elementwise_max(vn[j], acc);
            }
        }
        vc[0] = vn[0]; vc[1] = vn[1];
    }

    // ---- write out: lane l -> column l, rows 4w..4w+3 (coalesced per wave) ----
    float* ob = out + (size_t)b*HW*HW + (size_t)(4*w)*HW + l;
    ob[0*HW] = vc[0].x;
    ob[1*HW] = vc[0].y;
    ob[2*HW] = vc[1].x;
    ob[3*HW] = vc[1].y;
}

extern "C" void kernel_launch(void* const* d_in, const int* in_sizes, int n_in,
                              void* d_out, int out_size, void* d_ws, size_t ws_size,
                              hipStream_t stream) {
    const float* X   = (const float*)d_in[0];
    const float* h_w = (const float*)d_in[1];
    const float* h_b = (const float*)d_in[2];
    const float* r_w = (const float*)d_in[3];
    const float* q_w = (const float*)d_in[4];
    const float* w   = (const float*)d_in[5];
    const int*   k   = (const int*)d_in[6];
    float* out = (float*)d_out;

    vin_main<<<128, 1024, 0, stream>>>(X, h_w, h_b, r_w, q_w, w, k, out);
}